// Round 10
// baseline (163.704 us; speedup 1.0000x reference)
//
#include <hip/hip_runtime.h>
#include <hip/hip_bf16.h>

#define SLOPE 0.1f
typedef unsigned short u16;
typedef unsigned int u32;
typedef __attribute__((ext_vector_type(8))) short short8;
typedef __attribute__((ext_vector_type(4))) float floatx4;

__device__ __forceinline__ float lrelu(float x) { return x > 0.0f ? x : SLOPE * x; }

// round-nearest split: x ~= hi + lo (bf16 each), rel err ~2^-17
__device__ __forceinline__ void split_rn(float x, u16* h, u16* l) {
    union { __hip_bfloat16 b; u16 u; } c1, c2;
    c1.b = __float2bfloat16(x);
    float hf = __bfloat162float(c1.b);
    c2.b = __float2bfloat16(x - hf);
    *h = c1.u; *l = c2.u;
}

// truncation split of a PAIR of fp32 -> packed hi-u32 and lo-u32 (v_perm pack)
__device__ __forceinline__ void pack2x2(float v0, float v1, u32& h, u32& l) {
    u32 a0 = __float_as_uint(v0), a1 = __float_as_uint(v1);
    h = __builtin_amdgcn_perm(a1, a0, 0x07060302u);   // [a0.hi16 | a1.hi16]
    float r0 = v0 - __uint_as_float(a0 & 0xFFFF0000u);
    float r1 = v1 - __uint_as_float(a1 & 0xFFFF0000u);
    l = __builtin_amdgcn_perm(__float_as_uint(r1), __float_as_uint(r0), 0x07060302u);
}

__device__ __forceinline__ short8 load_frag(const u16* p) {
    union { uint4 q; short8 s; } cv;
    cv.q = *(const uint4*)p;
    return cv.s;
}

__device__ __forceinline__ floatx4 mfma16(short8 a, short8 b, floatx4 c) {
    return __builtin_amdgcn_mfma_f32_16x16x32_bf16(a, b, c, 0, 0, 0);
}

// ---------------------------------------------------------------------------
// P0: one-shot preprocessing into FRAGMENT-LINEAR layouts, x4 vectorized.
// ---------------------------------------------------------------------------
__global__ __launch_bounds__(256) void p0_prep(
    const float* __restrict__ x,
    const float* __restrict__ cw0, const float* __restrict__ cw1,
    const float* __restrict__ cw2, const float* __restrict__ cw3,
    const float* __restrict__ mw0, const float* __restrict__ mw1,
    const float* __restrict__ mw2, const float* __restrict__ mw3,
    const float* __restrict__ lw0, const float* __restrict__ lw1,
    u16* __restrict__ xfh, u16* __restrict__ xfl,
    u16* __restrict__ wcfh, u16* __restrict__ wcfl,
    u16* __restrict__ b2fh, u16* __restrict__ b2fl,
    u16* __restrict__ w3fh, u16* __restrict__ w3fl,
    float* __restrict__ lw0t, float* __restrict__ lw1t)
{
    int idx = (blockIdx.x * 256 + threadIdx.x) * 4;
    if (idx < 1048576) {
        const int j = idx & 7, lane = (idx >> 3) & 63;
        const int kc = (idx >> 9) & 15, rt = idx >> 13;
        const int l15 = lane & 15, quad = lane >> 4;
        const float4 s = *(const float4*)(x + (rt * 16 + l15) * 512 + kc * 32 + quad * 8 + j);
        u16 h[4], l[4];
        split_rn(s.x, &h[0], &l[0]); split_rn(s.y, &h[1], &l[1]);
        split_rn(s.z, &h[2], &l[2]); split_rn(s.w, &h[3], &l[3]);
        *(ushort4*)(xfh + idx) = make_ushort4(h[0], h[1], h[2], h[3]);
        *(ushort4*)(xfl + idx) = make_ushort4(l[0], l[1], l[2], l[3]);
        return;
    }
    idx -= 1048576;
    if (idx < 524288) {
        const int j = idx & 7, lane = (idx >> 3) & 63;
        const int kc = (idx >> 9) & 15, nt = (idx >> 13) & 3, slot = idx >> 15;
        int branch, base;
        if (slot == 0)      { branch = 0; base = 0; }
        else if (slot < 4)  { branch = 1; base = 1; }
        else if (slot < 9)  { branch = 2; base = 4; }
        else                { branch = 3; base = 9; }
        const int dk = slot - base, ksz = 2 * branch + 1;
        const float* cw = branch == 0 ? cw0 : branch == 1 ? cw1 : branch == 2 ? cw2 : cw3;
        const int c = nt * 16 + (lane & 15);
        const int e = kc * 32 + (lane >> 4) * 8 + j;
        const float4 s = *(const float4*)(cw + (c * ksz + dk) * 512 + e);
        u16 h[4], l[4];
        split_rn(s.x, &h[0], &l[0]); split_rn(s.y, &h[1], &l[1]);
        split_rn(s.z, &h[2], &l[2]); split_rn(s.w, &h[3], &l[3]);
        *(ushort4*)(wcfh + idx) = make_ushort4(h[0], h[1], h[2], h[3]);
        *(ushort4*)(wcfl + idx) = make_ushort4(l[0], l[1], l[2], l[3]);
        return;
    }
    idx -= 524288;
    if (idx < 32768) {
        const int j = idx & 7, lane = (idx >> 3) & 63;
        const int kc = (idx >> 9) & 7, nt = (idx >> 12) & 3, nh = idx >> 14;
        const int n = nh * 64 + nt * 16 + (lane & 15);
        const int k = kc * 32 + (lane >> 4) * 8 + j;
        const float4 s = *(const float4*)(mw0 + (n & 63) * 512 + (n >> 6) * 256 + k);
        u16 h[4], l[4];
        split_rn(s.x, &h[0], &l[0]); split_rn(s.y, &h[1], &l[1]);
        split_rn(s.z, &h[2], &l[2]); split_rn(s.w, &h[3], &l[3]);
        *(ushort4*)(b2fh + idx) = make_ushort4(h[0], h[1], h[2], h[3]);
        *(ushort4*)(b2fl + idx) = make_ushort4(l[0], l[1], l[2], l[3]);
        return;
    }
    idx -= 32768;
    if (idx < 12288) {
        const int j = idx & 7, lane = (idx >> 3) & 63;
        const int kc = (idx >> 9) & 1, mt = (idx >> 10) & 3, layer = idx >> 12;
        const float* mw = layer == 0 ? mw1 : layer == 1 ? mw2 : mw3;
        const int ch = mt * 16 + (lane & 15);
        const int k = kc * 32 + (lane >> 4) * 8 + j;
        const float4 s = *(const float4*)(mw + ch * 64 + k);
        u16 h[4], l[4];
        split_rn(s.x, &h[0], &l[0]); split_rn(s.y, &h[1], &l[1]);
        split_rn(s.z, &h[2], &l[2]); split_rn(s.w, &h[3], &l[3]);
        *(ushort4*)(w3fh + idx) = make_ushort4(h[0], h[1], h[2], h[3]);
        *(ushort4*)(w3fl + idx) = make_ushort4(l[0], l[1], l[2], l[3]);
        return;
    }
    idx -= 12288;
    if (idx < 4096) {
        const int k = idx >> 6, n = idx & 63;
        float4 o;
        o.x = lw0[(n + 0) * 64 + k]; o.y = lw0[(n + 1) * 64 + k];
        o.z = lw0[(n + 2) * 64 + k]; o.w = lw0[(n + 3) * 64 + k];
        *(float4*)(lw0t + idx) = o;
        return;
    }
    idx -= 4096;
    if (idx < 16384) {
        const int k = idx >> 8, n = idx & 255;
        float4 o;
        o.x = lw1[(n + 0) * 64 + k]; o.y = lw1[(n + 1) * 64 + k];
        o.z = lw1[(n + 2) * 64 + k]; o.w = lw1[(n + 3) * 64 + k];
        *(float4*)(lw1t + idx) = o;
        return;
    }
}

// ---------------------------------------------------------------------------
// K1f: fused conv GEMM, LOAD-BALANCED (from R9): grid (128 rt, 2 halves).
// half0 = branches {0,1,2} (144 K-units), half1 = branch {3} (112 units).
// ---------------------------------------------------------------------------
__global__ __launch_bounds__(512) void k1f_conv(
    const u16* __restrict__ xfh, const u16* __restrict__ xfl,
    const u16* __restrict__ wcfh, const u16* __restrict__ wcfl,
    const float* __restrict__ cb0, const float* __restrict__ cb1,
    const float* __restrict__ cb2, const float* __restrict__ cb3,
    u16* __restrict__ Ffh, u16* __restrict__ Ffl)
{
    __shared__ float P[8][16][72];   // 36.9 KB

    const int t = threadIdx.x, lane = t & 63, w = t >> 6;   // 8 waves
    const int rt = blockIdx.x;                 // 0..127
    const int half = blockIdx.y;               // 0: br 0..2, 1: br 3
    const int l15 = lane & 15, quad = lane >> 4;
    const int row = (t & 255) >> 4, c4 = (t & 15) * 4;

    if (half == 0) {
        floatx4 acc[3][4];
        #pragma unroll
        for (int br = 0; br < 3; ++br)
            #pragma unroll
            for (int j = 0; j < 4; ++j) acc[br][j] = (floatx4)0.0f;

        #pragma unroll
        for (int br = 0; br < 3; ++br) {
            const int base = br * br, ksz = 2 * br + 1;
            for (int unit = w; unit < ksz * 16; unit += 8) {
                const int dk = unit >> 4, kc = unit & 15;
                const int rts = rt + dk - br;
                if (rts < 0 || rts >= 128) continue;
                const int slot = base + dk;
                const int aoff = ((rts * 16 + kc) * 64 + lane) * 8;
                const short8 ah = load_frag(xfh + aoff);
                const short8 al = load_frag(xfl + aoff);
                #pragma unroll
                for (int nt = 0; nt < 4; ++nt) {
                    const int boff = (((slot * 4 + nt) * 16 + kc) * 64 + lane) * 8;
                    const short8 bh = load_frag(wcfh + boff);
                    const short8 bl = load_frag(wcfl + boff);
                    acc[br][nt] = mfma16(ah, bh, acc[br][nt]);
                    acc[br][nt] = mfma16(ah, bl, acc[br][nt]);
                    acc[br][nt] = mfma16(al, bh, acc[br][nt]);
                }
            }
        }

        #pragma unroll
        for (int br = 0; br < 3; ++br) {
            #pragma unroll
            for (int nt = 0; nt < 4; ++nt)
                #pragma unroll
                for (int rr = 0; rr < 4; ++rr)
                    P[w][quad * 4 + rr][nt * 16 + l15] = acc[br][nt][rr];
            __syncthreads();
            if (t < 256) {
                const float* cb = br == 0 ? cb0 : br == 1 ? cb1 : cb2;
                u16 h4[4], l4[4];
                #pragma unroll
                for (int i = 0; i < 4; ++i) {
                    float val = cb[c4 + i];
                    #pragma unroll
                    for (int ww = 0; ww < 8; ++ww) val += P[ww][row][c4 + i];
                    split_rn(lrelu(val), &h4[i], &l4[i]);
                }
                const int m4 = br * 64 + c4;
                const int dst = ((rt * 8 + (m4 >> 5)) * 64 + ((m4 >> 3) & 3) * 16 + row) * 8 + (m4 & 7);
                *(ushort4*)(Ffh + dst) = make_ushort4(h4[0], h4[1], h4[2], h4[3]);
                *(ushort4*)(Ffl + dst) = make_ushort4(l4[0], l4[1], l4[2], l4[3]);
            }
            __syncthreads();
        }
    } else {
        floatx4 acc[4];
        #pragma unroll
        for (int j = 0; j < 4; ++j) acc[j] = (floatx4)0.0f;

        for (int unit = w; unit < 112; unit += 8) {     // br=3, 7 taps
            const int dk = unit >> 4, kc = unit & 15;
            const int rts = rt + dk - 3;
            if (rts < 0 || rts >= 128) continue;
            const int slot = 9 + dk;
            const int aoff = ((rts * 16 + kc) * 64 + lane) * 8;
            const short8 ah = load_frag(xfh + aoff);
            const short8 al = load_frag(xfl + aoff);
            #pragma unroll
            for (int nt = 0; nt < 4; ++nt) {
                const int boff = (((slot * 4 + nt) * 16 + kc) * 64 + lane) * 8;
                const short8 bh = load_frag(wcfh + boff);
                const short8 bl = load_frag(wcfl + boff);
                acc[nt] = mfma16(ah, bh, acc[nt]);
                acc[nt] = mfma16(ah, bl, acc[nt]);
                acc[nt] = mfma16(al, bh, acc[nt]);
            }
        }

        #pragma unroll
        for (int nt = 0; nt < 4; ++nt)
            #pragma unroll
            for (int rr = 0; rr < 4; ++rr)
                P[w][quad * 4 + rr][nt * 16 + l15] = acc[nt][rr];
        __syncthreads();
        if (t < 256) {
            u16 h4[4], l4[4];
            #pragma unroll
            for (int i = 0; i < 4; ++i) {
                float val = cb3[c4 + i];
                #pragma unroll
                for (int ww = 0; ww < 8; ++ww) val += P[ww][row][c4 + i];
                split_rn(lrelu(val), &h4[i], &l4[i]);
            }
            const int m4 = 192 + c4;
            const int dst = ((rt * 8 + (m4 >> 5)) * 64 + ((m4 >> 3) & 3) * 16 + row) * 8 + (m4 & 7);
            *(ushort4*)(Ffh + dst) = make_ushort4(h4[0], h4[1], h4[2], h4[3]);
            *(ushort4*)(Ffl + dst) = make_ushort4(l4[0], l4[1], l4[2], l4[3]);
        }
    }
}

// ---------------------------------------------------------------------------
// K2: [u|v] = F @ B2^T.  grid (128 rt, 2 nh); 4 waves, each 2 kc; LDS reduce.
// u gets +mb0; v written transposed (b-major) as v_t.
// ---------------------------------------------------------------------------
__global__ __launch_bounds__(256) void k2_uv(
    const u16* __restrict__ Ffh, const u16* __restrict__ Ffl,
    const u16* __restrict__ b2fh, const u16* __restrict__ b2fl,
    const float* __restrict__ mb0,
    float* __restrict__ u, float* __restrict__ v_t)
{
    __shared__ float P[4][16][72];

    const int t = threadIdx.x, lane = t & 63, w = t >> 6;
    const int rt = blockIdx.x;
    const int nh = blockIdx.y;
    const int l15 = lane & 15, quad = lane >> 4;

    floatx4 acc[4];
    #pragma unroll
    for (int j = 0; j < 4; ++j) acc[j] = (floatx4)0.0f;

    #pragma unroll
    for (int kk = 0; kk < 2; ++kk) {
        const int kc = w * 2 + kk;
        const int aoff = ((rt * 8 + kc) * 64 + lane) * 8;
        const short8 ah = load_frag(Ffh + aoff);
        const short8 al = load_frag(Ffl + aoff);
        #pragma unroll
        for (int nt = 0; nt < 4; ++nt) {
            const int boff = (((nh * 4 + nt) * 8 + kc) * 64 + lane) * 8;
            const short8 bh = load_frag(b2fh + boff);
            const short8 bl = load_frag(b2fl + boff);
            acc[nt] = mfma16(ah, bh, acc[nt]);
            acc[nt] = mfma16(ah, bl, acc[nt]);
            acc[nt] = mfma16(al, bh, acc[nt]);
        }
    }

    #pragma unroll
    for (int nt = 0; nt < 4; ++nt)
        #pragma unroll
        for (int r = 0; r < 4; ++r)
            P[w][quad * 4 + r][nt * 16 + l15] = acc[nt][r];
    __syncthreads();

    const int row = t >> 4, c4 = (t & 15) * 4;
    const int rglob = rt * 16 + row;
    float4 oo;
    #pragma unroll
    for (int i = 0; i < 4; ++i)
        (&oo.x)[i] = P[0][row][c4 + i] + P[1][row][c4 + i]
                   + P[2][row][c4 + i] + P[3][row][c4 + i];
    if (nh == 0) {
        oo.x += mb0[c4 + 0]; oo.y += mb0[c4 + 1];
        oo.z += mb0[c4 + 2]; oo.w += mb0[c4 + 3];
        *(float4*)(u + rglob * 64 + c4) = oo;
    } else {
        const int i = rglob >> 4, b = rglob & 15;
        *(float4*)(v_t + (b * 128 + i) * 64 + c4) = oo;
    }
}

// ---------------------------------------------------------------------------
// K3 (R8 structure): per jb, 4 waves x 32 i's; H bf16 hi/lo in LDS, rows
// wave-private; fully barrier-free.  Layer-3 reduced over own 32 i in regs
// (shfl) -> Spart quarter per wave (global).  NO fused head (head weights
// would thrash L1/L2 at 2048 blocks — R9 lesson).
// grid: 2048 blocks, 256 thr; LDS 36.9 KB -> 4 blocks/CU -> 16 waves/CU.
// ---------------------------------------------------------------------------
__global__ __launch_bounds__(256, 4) void k3_pair(
    const float* __restrict__ u, const float* __restrict__ v_t,
    const u16* __restrict__ w3fh, const u16* __restrict__ w3fl,
    const float* __restrict__ mb1, const float* __restrict__ mb2,
    const float* __restrict__ mb3,
    float* __restrict__ Spart)
{
    __shared__ __align__(16) u16 Hh[128][72];
    __shared__ __align__(16) u16 Hl[128][72];

    const int t = threadIdx.x, lane = t & 63, w = t >> 6;   // w in {0..3}
    const int jb = blockIdx.x, b = jb & 15;
    const int l15 = lane & 15, quad = lane >> 4;
    const int i0 = w * 32;                       // wave's 32-i strip
    const int c4 = l15 * 4;

    // u row: loop-invariant per lane (one global float4, L1/L2-hot)
    const float4 uu = *(const float4*)(u + jb * 64 + c4);

    // H1 build: contiguous 8 KB stream per wave from v_t
    const float* vb = v_t + (b * 128 + i0) * 64;
    #pragma unroll
    for (int n = 0; n < 8; ++n) {
        const int idx = n * 64 + lane;
        const int il = idx >> 4;                  // c4 == (idx&15)*4 == l15*4
        const float4 vv = *(const float4*)(vb + idx * 4);
        const float a0 = lrelu(vv.x + uu.x), a1 = lrelu(vv.y + uu.y);
        const float a2 = lrelu(vv.z + uu.z), a3 = lrelu(vv.w + uu.w);
        u32 h01, l01, h23, l23;
        pack2x2(a0, a1, h01, l01);
        pack2x2(a2, a3, h23, l23);
        *(uint2*)&Hh[i0 + il][c4] = make_uint2(h01, h23);
        *(uint2*)&Hl[i0 + il][c4] = make_uint2(l01, l23);
    }

    const float* mbp[3] = {mb1, mb2, mb3};
    for (int layer = 0; layer < 3; ++layer) {
        floatx4 acc[4][2];                       // [mt=ch][nt=i]
        #pragma unroll
        for (int i = 0; i < 4; ++i)
            #pragma unroll
            for (int j = 0; j < 2; ++j) acc[i][j] = (floatx4)0.0f;

        #pragma unroll
        for (int kc = 0; kc < 2; ++kc) {
            short8 ah[4], al[4];
            #pragma unroll
            for (int mt = 0; mt < 4; ++mt) {
                const int aoff = (((layer * 4 + mt) * 2 + kc) * 64 + lane) * 8;
                ah[mt] = load_frag(w3fh + aoff);
                al[mt] = load_frag(w3fl + aoff);
            }
            const int k0 = kc * 32 + quad * 8;
            #pragma unroll
            for (int nt = 0; nt < 2; ++nt) {
                const short8 bh = load_frag(&Hh[i0 + nt * 16 + l15][k0]);
                const short8 bl = load_frag(&Hl[i0 + nt * 16 + l15][k0]);
                #pragma unroll
                for (int mt = 0; mt < 4; ++mt) {
                    acc[mt][nt] = mfma16(ah[mt], bh, acc[mt][nt]);
                    acc[mt][nt] = mfma16(ah[mt], bl, acc[mt][nt]);
                    acc[mt][nt] = mfma16(al[mt], bh, acc[mt][nt]);
                }
            }
        }

        if (layer < 2) {
            #pragma unroll
            for (int mt = 0; mt < 4; ++mt) {
                float bias[4];
                #pragma unroll
                for (int r = 0; r < 4; ++r) bias[r] = mbp[layer][mt * 16 + quad * 4 + r];
                #pragma unroll
                for (int nt = 0; nt < 2; ++nt) {
                    const int i = i0 + nt * 16 + l15;
                    const float v0 = lrelu(acc[mt][nt][0] + bias[0]);
                    const float v1 = lrelu(acc[mt][nt][1] + bias[1]);
                    const float v2 = lrelu(acc[mt][nt][2] + bias[2]);
                    const float v3 = lrelu(acc[mt][nt][3] + bias[3]);
                    u32 h01, l01, h23, l23;
                    pack2x2(v0, v1, h01, l01);
                    pack2x2(v2, v3, h23, l23);
                    *(uint2*)&Hh[i][mt * 16 + quad * 4] = make_uint2(h01, h23);
                    *(uint2*)&Hl[i][mt * 16 + quad * 4] = make_uint2(l01, l23);
                }
            }
        } else {
            // final layer: lrelu + reduce over this wave's 32 i
            #pragma unroll
            for (int mt = 0; mt < 4; ++mt) {
                float bias[4];
                #pragma unroll
                for (int r = 0; r < 4; ++r) bias[r] = mbp[2][mt * 16 + quad * 4 + r];
                float4 sv;
                #pragma unroll
                for (int r = 0; r < 4; ++r) {
                    float val = lrelu(acc[mt][0][r] + bias[r])
                              + lrelu(acc[mt][1][r] + bias[r]);
                    val += __shfl_xor(val, 1, 16);
                    val += __shfl_xor(val, 2, 16);
                    val += __shfl_xor(val, 4, 16);
                    val += __shfl_xor(val, 8, 16);
                    (&sv.x)[r] = val;
                }
                if (l15 == 0)
                    *(float4*)(Spart + jb * 256 + w * 64 + mt * 16 + quad * 4) = sv;
            }
        }
    }
}

// ---------------------------------------------------------------------------
// K4: head over 8 jb per block (weights amortized; R8 structure).
// S = 4 Spart quarters summed; T1 = lrelu(S@lw0t+lb0); out = lrelu(T1@lw1t+lb1).
// grid: 256 blocks, 256 thr.
// ---------------------------------------------------------------------------
__global__ __launch_bounds__(256) void k4_head(
    const float* __restrict__ Spart,
    const float* __restrict__ lw0t, const float* __restrict__ lb0,
    const float* __restrict__ lw1t, const float* __restrict__ lb1,
    float* __restrict__ out)
{
    __shared__ float Ss[8][64];
    __shared__ float T1[8][64];

    const int t = threadIdx.x;
    const int jb0 = blockIdx.x * 8;

    #pragma unroll
    for (int p = 0; p < 2; ++p) {
        const int idx = t + 256 * p;
        const int jbb = idx >> 6, ch = idx & 63;
        const float* sp = Spart + (jb0 + jbb) * 256 + ch;
        Ss[jbb][ch] = sp[0] + sp[64] + sp[128] + sp[192];
    }
    __syncthreads();

    #pragma unroll
    for (int p = 0; p < 2; ++p) {
        const int idx = t + 256 * p;
        const int jbb = idx >> 6, c = idx & 63;
        float a = lb0[c];
        #pragma unroll 8
        for (int k = 0; k < 64; ++k) a += Ss[jbb][k] * lw0t[k * 64 + c];
        T1[jbb][c] = lrelu(a);
    }
    __syncthreads();

    const int c = t;
    float acc[8];
    const float base = lb1[c];
    #pragma unroll
    for (int jbb = 0; jbb < 8; ++jbb) acc[jbb] = base;
    #pragma unroll 4
    for (int k = 0; k < 64; ++k) {
        const float wv = lw1t[k * 256 + c];
        #pragma unroll
        for (int jbb = 0; jbb < 8; ++jbb) acc[jbb] += T1[jbb][k] * wv;
    }
    #pragma unroll
    for (int jbb = 0; jbb < 8; ++jbb)
        out[(jb0 + jbb) * 256 + c] = lrelu(acc[jbb]);
}

// ---------------------------------------------------------------------------
extern "C" void kernel_launch(void* const* d_in, const int* in_sizes, int n_in,
                              void* d_out, int out_size, void* d_ws, size_t ws_size,
                              hipStream_t stream)
{
    const float* x   = (const float*)d_in[0];
    const float* cw0 = (const float*)d_in[1];
    const float* cb0 = (const float*)d_in[2];
    const float* cw1 = (const float*)d_in[3];
    const float* cb1 = (const float*)d_in[4];
    const float* cw2 = (const float*)d_in[5];
    const float* cb2 = (const float*)d_in[6];
    const float* cw3 = (const float*)d_in[7];
    const float* cb3 = (const float*)d_in[8];
    const float* mw0 = (const float*)d_in[9];
    const float* mb0 = (const float*)d_in[10];
    const float* mw1 = (const float*)d_in[11];
    const float* mb1 = (const float*)d_in[12];
    const float* mw2 = (const float*)d_in[13];
    const float* mb2 = (const float*)d_in[14];
    const float* mw3 = (const float*)d_in[15];
    const float* mb3 = (const float*)d_in[16];
    const float* lw0 = (const float*)d_in[17];
    const float* lb0 = (const float*)d_in[18];
    const float* lw1 = (const float*)d_in[19];
    const float* lb1 = (const float*)d_in[20];
    float* out = (float*)d_out;

    char* base = (char*)d_ws;
    u16* xfh   = (u16*)(base + 0);
    u16* xfl   = (u16*)(base + 2097152);
    u16* wcfh  = (u16*)(base + 4194304);
    u16* wcfl  = (u16*)(base + 5242880);
    u16* b2fh  = (u16*)(base + 6291456);
    u16* b2fl  = (u16*)(base + 6356992);
    u16* w3fh  = (u16*)(base + 6422528);
    u16* w3fl  = (u16*)(base + 6447104);
    float* lw0t  = (float*)(base + 6471680);
    float* lw1t  = (float*)(base + 6488064);
    u16* Ffh   = (u16*)(base + 6553600);
    u16* Ffl   = (u16*)(base + 7602176);
    float* u   = (float*)(base + 8650752);
    float* v_t = (float*)(base + 9175040);
    float* Spart = (float*)(base + 9699328);   // 2048*256*4 = 2 MB
    // total 11796480 bytes (~11.3 MB)

    hipLaunchKernelGGL(p0_prep, dim3(1600), dim3(256), 0, stream,
                       x, cw0, cw1, cw2, cw3, mw0, mw1, mw2, mw3, lw0, lw1,
                       xfh, xfl, wcfh, wcfl, b2fh, b2fl, w3fh, w3fl, lw0t, lw1t);
    hipLaunchKernelGGL(k1f_conv, dim3(128, 2), dim3(512), 0, stream,
                       xfh, xfl, wcfh, wcfl, cb0, cb1, cb2, cb3, Ffh, Ffl);
    hipLaunchKernelGGL(k2_uv, dim3(128, 2), dim3(256), 0, stream,
                       Ffh, Ffl, b2fh, b2fl, mb0, u, v_t);
    hipLaunchKernelGGL(k3_pair, dim3(2048), dim3(256), 0, stream,
                       u, v_t, w3fh, w3fl, mb1, mb2, mb3, Spart);
    hipLaunchKernelGGL(k4_head, dim3(256), dim3(256), 0, stream,
                       Spart, lw0t, lb0, lw1t, lb1, out);
}

// Round 11
// 156.815 us; speedup vs baseline: 1.0439x; 1.0439x over previous
//
#include <hip/hip_runtime.h>
#include <hip/hip_bf16.h>

#define SLOPE 0.1f
typedef unsigned short u16;
typedef unsigned int u32;
typedef __attribute__((ext_vector_type(8))) short short8;
typedef __attribute__((ext_vector_type(4))) float floatx4;

__device__ __forceinline__ float lrelu(float x) { return x > 0.0f ? x : SLOPE * x; }

// round-nearest split: x ~= hi + lo (bf16 each), rel err ~2^-17
__device__ __forceinline__ void split_rn(float x, u16* h, u16* l) {
    union { __hip_bfloat16 b; u16 u; } c1, c2;
    c1.b = __float2bfloat16(x);
    float hf = __bfloat162float(c1.b);
    c2.b = __float2bfloat16(x - hf);
    *h = c1.u; *l = c2.u;
}

// truncation split of a PAIR of fp32 -> packed hi-u32 and lo-u32 (v_perm pack)
__device__ __forceinline__ void pack2x2(float v0, float v1, u32& h, u32& l) {
    u32 a0 = __float_as_uint(v0), a1 = __float_as_uint(v1);
    h = __builtin_amdgcn_perm(a1, a0, 0x07060302u);   // [a0.hi16 | a1.hi16]
    float r0 = v0 - __uint_as_float(a0 & 0xFFFF0000u);
    float r1 = v1 - __uint_as_float(a1 & 0xFFFF0000u);
    l = __builtin_amdgcn_perm(__float_as_uint(r1), __float_as_uint(r0), 0x07060302u);
}

__device__ __forceinline__ short8 load_frag(const u16* p) {
    union { uint4 q; short8 s; } cv;
    cv.q = *(const uint4*)p;
    return cv.s;
}

__device__ __forceinline__ floatx4 mfma16(short8 a, short8 b, floatx4 c) {
    return __builtin_amdgcn_mfma_f32_16x16x32_bf16(a, b, c, 0, 0, 0);
}

// ---------------------------------------------------------------------------
// P0: one-shot preprocessing into FRAGMENT-LINEAR layouts, x4 vectorized.
// ---------------------------------------------------------------------------
__global__ __launch_bounds__(256) void p0_prep(
    const float* __restrict__ x,
    const float* __restrict__ cw0, const float* __restrict__ cw1,
    const float* __restrict__ cw2, const float* __restrict__ cw3,
    const float* __restrict__ mw0, const float* __restrict__ mw1,
    const float* __restrict__ mw2, const float* __restrict__ mw3,
    const float* __restrict__ lw0, const float* __restrict__ lw1,
    u16* __restrict__ xfh, u16* __restrict__ xfl,
    u16* __restrict__ wcfh, u16* __restrict__ wcfl,
    u16* __restrict__ b2fh, u16* __restrict__ b2fl,
    u16* __restrict__ w3fh, u16* __restrict__ w3fl,
    float* __restrict__ lw0t, float* __restrict__ lw1t)
{
    int idx = (blockIdx.x * 256 + threadIdx.x) * 4;
    if (idx < 1048576) {
        const int j = idx & 7, lane = (idx >> 3) & 63;
        const int kc = (idx >> 9) & 15, rt = idx >> 13;
        const int l15 = lane & 15, quad = lane >> 4;
        const float4 s = *(const float4*)(x + (rt * 16 + l15) * 512 + kc * 32 + quad * 8 + j);
        u16 h[4], l[4];
        split_rn(s.x, &h[0], &l[0]); split_rn(s.y, &h[1], &l[1]);
        split_rn(s.z, &h[2], &l[2]); split_rn(s.w, &h[3], &l[3]);
        *(ushort4*)(xfh + idx) = make_ushort4(h[0], h[1], h[2], h[3]);
        *(ushort4*)(xfl + idx) = make_ushort4(l[0], l[1], l[2], l[3]);
        return;
    }
    idx -= 1048576;
    if (idx < 524288) {
        const int j = idx & 7, lane = (idx >> 3) & 63;
        const int kc = (idx >> 9) & 15, nt = (idx >> 13) & 3, slot = idx >> 15;
        int branch, base;
        if (slot == 0)      { branch = 0; base = 0; }
        else if (slot < 4)  { branch = 1; base = 1; }
        else if (slot < 9)  { branch = 2; base = 4; }
        else                { branch = 3; base = 9; }
        const int dk = slot - base, ksz = 2 * branch + 1;
        const float* cw = branch == 0 ? cw0 : branch == 1 ? cw1 : branch == 2 ? cw2 : cw3;
        const int c = nt * 16 + (lane & 15);
        const int e = kc * 32 + (lane >> 4) * 8 + j;
        const float4 s = *(const float4*)(cw + (c * ksz + dk) * 512 + e);
        u16 h[4], l[4];
        split_rn(s.x, &h[0], &l[0]); split_rn(s.y, &h[1], &l[1]);
        split_rn(s.z, &h[2], &l[2]); split_rn(s.w, &h[3], &l[3]);
        *(ushort4*)(wcfh + idx) = make_ushort4(h[0], h[1], h[2], h[3]);
        *(ushort4*)(wcfl + idx) = make_ushort4(l[0], l[1], l[2], l[3]);
        return;
    }
    idx -= 524288;
    if (idx < 32768) {
        const int j = idx & 7, lane = (idx >> 3) & 63;
        const int kc = (idx >> 9) & 7, nt = (idx >> 12) & 3, nh = idx >> 14;
        const int n = nh * 64 + nt * 16 + (lane & 15);
        const int k = kc * 32 + (lane >> 4) * 8 + j;
        const float4 s = *(const float4*)(mw0 + (n & 63) * 512 + (n >> 6) * 256 + k);
        u16 h[4], l[4];
        split_rn(s.x, &h[0], &l[0]); split_rn(s.y, &h[1], &l[1]);
        split_rn(s.z, &h[2], &l[2]); split_rn(s.w, &h[3], &l[3]);
        *(ushort4*)(b2fh + idx) = make_ushort4(h[0], h[1], h[2], h[3]);
        *(ushort4*)(b2fl + idx) = make_ushort4(l[0], l[1], l[2], l[3]);
        return;
    }
    idx -= 32768;
    if (idx < 12288) {
        const int j = idx & 7, lane = (idx >> 3) & 63;
        const int kc = (idx >> 9) & 1, mt = (idx >> 10) & 3, layer = idx >> 12;
        const float* mw = layer == 0 ? mw1 : layer == 1 ? mw2 : mw3;
        const int ch = mt * 16 + (lane & 15);
        const int k = kc * 32 + (lane >> 4) * 8 + j;
        const float4 s = *(const float4*)(mw + ch * 64 + k);
        u16 h[4], l[4];
        split_rn(s.x, &h[0], &l[0]); split_rn(s.y, &h[1], &l[1]);
        split_rn(s.z, &h[2], &l[2]); split_rn(s.w, &h[3], &l[3]);
        *(ushort4*)(w3fh + idx) = make_ushort4(h[0], h[1], h[2], h[3]);
        *(ushort4*)(w3fl + idx) = make_ushort4(l[0], l[1], l[2], l[3]);
        return;
    }
    idx -= 12288;
    if (idx < 4096) {
        const int k = idx >> 6, n = idx & 63;
        float4 o;
        o.x = lw0[(n + 0) * 64 + k]; o.y = lw0[(n + 1) * 64 + k];
        o.z = lw0[(n + 2) * 64 + k]; o.w = lw0[(n + 3) * 64 + k];
        *(float4*)(lw0t + idx) = o;
        return;
    }
    idx -= 4096;
    if (idx < 16384) {
        const int k = idx >> 8, n = idx & 255;
        float4 o;
        o.x = lw1[(n + 0) * 64 + k]; o.y = lw1[(n + 1) * 64 + k];
        o.z = lw1[(n + 2) * 64 + k]; o.w = lw1[(n + 3) * 64 + k];
        *(float4*)(lw1t + idx) = o;
        return;
    }
}

// ---------------------------------------------------------------------------
// K1f: fused conv GEMM, 2-rt tiling (PROVEN R8): block = (rt-pair, branch),
// 512 thr = 8 waves, K-split 8-way over (dk,kc) units.  B (weight) frags
// loaded once per unit and reused for both rt -> weight L2 traffic halved.
// Two-phase LDS reduce + bias/lrelu/split epilogue -> F frag-linear.
// grid: (64, 4).
// ---------------------------------------------------------------------------
__global__ __launch_bounds__(512) void k1f_conv(
    const u16* __restrict__ xfh, const u16* __restrict__ xfl,
    const u16* __restrict__ wcfh, const u16* __restrict__ wcfl,
    const float* __restrict__ cb0, const float* __restrict__ cb1,
    const float* __restrict__ cb2, const float* __restrict__ cb3,
    u16* __restrict__ Ffh, u16* __restrict__ Ffl)
{
    __shared__ float P[8][16][72];   // 36.9 KB

    const int t = threadIdx.x, lane = t & 63, w = t >> 6;   // 8 waves
    const int rtp = blockIdx.x;                // 0..63 -> rt, rt+64
    const int br = blockIdx.y;                 // 0..3
    const int base = br * br;                  // 0,1,4,9
    const int ksz = 2 * br + 1;
    const int l15 = lane & 15, quad = lane >> 4;

    floatx4 acc[2][4];
    #pragma unroll
    for (int r = 0; r < 2; ++r)
        #pragma unroll
        for (int j = 0; j < 4; ++j) acc[r][j] = (floatx4)0.0f;

    const int nunits = ksz * 16;
    for (int unit = w; unit < nunits; unit += 8) {
        const int dk = unit >> 4, kc = unit & 15;
        const int slot = base + dk;
        short8 bh[4], bl[4];
        #pragma unroll
        for (int nt = 0; nt < 4; ++nt) {
            const int boff = (((slot * 4 + nt) * 16 + kc) * 64 + lane) * 8;
            bh[nt] = load_frag(wcfh + boff);
            bl[nt] = load_frag(wcfl + boff);
        }
        #pragma unroll
        for (int r = 0; r < 2; ++r) {
            const int rts = rtp + r * 64 + dk - br;
            if (rts < 0 || rts >= 128) continue;
            const int aoff = ((rts * 16 + kc) * 64 + lane) * 8;
            const short8 ah = load_frag(xfh + aoff);
            const short8 al = load_frag(xfl + aoff);
            #pragma unroll
            for (int nt = 0; nt < 4; ++nt) {
                acc[r][nt] = mfma16(ah, bh[nt], acc[r][nt]);
                acc[r][nt] = mfma16(ah, bl[nt], acc[r][nt]);
                acc[r][nt] = mfma16(al, bh[nt], acc[r][nt]);
            }
        }
    }

    const float* cb = br == 0 ? cb0 : br == 1 ? cb1 : br == 2 ? cb2 : cb3;
    #pragma unroll
    for (int r = 0; r < 2; ++r) {
        #pragma unroll
        for (int nt = 0; nt < 4; ++nt)
            #pragma unroll
            for (int rr = 0; rr < 4; ++rr)
                P[w][quad * 4 + rr][nt * 16 + l15] = acc[r][nt][rr];
        __syncthreads();
        if (t < 256) {
            const int row = t >> 4, c4 = (t & 15) * 4;
            u16 h4[4], l4[4];
            #pragma unroll
            for (int i = 0; i < 4; ++i) {
                float val = cb[c4 + i];
                #pragma unroll
                for (int ww = 0; ww < 8; ++ww) val += P[ww][row][c4 + i];
                split_rn(lrelu(val), &h4[i], &l4[i]);
            }
            const int rt = rtp + r * 64;
            const int m4 = br * 64 + c4;
            const int dst = ((rt * 8 + (m4 >> 5)) * 64 + ((m4 >> 3) & 3) * 16 + row) * 8 + (m4 & 7);
            *(ushort4*)(Ffh + dst) = make_ushort4(h4[0], h4[1], h4[2], h4[3]);
            *(ushort4*)(Ffl + dst) = make_ushort4(l4[0], l4[1], l4[2], l4[3]);
        }
        __syncthreads();
    }
}

// ---------------------------------------------------------------------------
// K2: [u|v] = F @ B2^T.  grid (128 rt, 2 nh); 4 waves, each 2 kc; LDS reduce.
// u gets +mb0; v written transposed (b-major) as v_t.
// ---------------------------------------------------------------------------
__global__ __launch_bounds__(256) void k2_uv(
    const u16* __restrict__ Ffh, const u16* __restrict__ Ffl,
    const u16* __restrict__ b2fh, const u16* __restrict__ b2fl,
    const float* __restrict__ mb0,
    float* __restrict__ u, float* __restrict__ v_t)
{
    __shared__ float P[4][16][72];

    const int t = threadIdx.x, lane = t & 63, w = t >> 6;
    const int rt = blockIdx.x;
    const int nh = blockIdx.y;
    const int l15 = lane & 15, quad = lane >> 4;

    floatx4 acc[4];
    #pragma unroll
    for (int j = 0; j < 4; ++j) acc[j] = (floatx4)0.0f;

    #pragma unroll
    for (int kk = 0; kk < 2; ++kk) {
        const int kc = w * 2 + kk;
        const int aoff = ((rt * 8 + kc) * 64 + lane) * 8;
        const short8 ah = load_frag(Ffh + aoff);
        const short8 al = load_frag(Ffl + aoff);
        #pragma unroll
        for (int nt = 0; nt < 4; ++nt) {
            const int boff = (((nh * 4 + nt) * 8 + kc) * 64 + lane) * 8;
            const short8 bh = load_frag(b2fh + boff);
            const short8 bl = load_frag(b2fl + boff);
            acc[nt] = mfma16(ah, bh, acc[nt]);
            acc[nt] = mfma16(ah, bl, acc[nt]);
            acc[nt] = mfma16(al, bh, acc[nt]);
        }
    }

    #pragma unroll
    for (int nt = 0; nt < 4; ++nt)
        #pragma unroll
        for (int r = 0; r < 4; ++r)
            P[w][quad * 4 + r][nt * 16 + l15] = acc[nt][r];
    __syncthreads();

    const int row = t >> 4, c4 = (t & 15) * 4;
    const int rglob = rt * 16 + row;
    float4 oo;
    #pragma unroll
    for (int i = 0; i < 4; ++i)
        (&oo.x)[i] = P[0][row][c4 + i] + P[1][row][c4 + i]
                   + P[2][row][c4 + i] + P[3][row][c4 + i];
    if (nh == 0) {
        oo.x += mb0[c4 + 0]; oo.y += mb0[c4 + 1];
        oo.z += mb0[c4 + 2]; oo.w += mb0[c4 + 3];
        *(float4*)(u + rglob * 64 + c4) = oo;
    } else {
        const int i = rglob >> 4, b = rglob & 15;
        *(float4*)(v_t + (b * 128 + i) * 64 + c4) = oo;
    }
}

// ---------------------------------------------------------------------------
// K3: per jb, 4 waves x 32 i's; H bf16 hi/lo in LDS, rows wave-private;
// fully barrier-free.  Layer-3 reduced over own 32 i in regs (shfl) ->
// Spart quarter per wave (global).  Head kept separate (R9 lesson: fused
// head re-reads 80 KB weights x 2048 blocks = 164 MB L2 thrash).
// grid: 2048 blocks, 256 thr; LDS 36.9 KB -> 4 blocks/CU -> 16 waves/CU.
// ---------------------------------------------------------------------------
__global__ __launch_bounds__(256, 4) void k3_pair(
    const float* __restrict__ u, const float* __restrict__ v_t,
    const u16* __restrict__ w3fh, const u16* __restrict__ w3fl,
    const float* __restrict__ mb1, const float* __restrict__ mb2,
    const float* __restrict__ mb3,
    float* __restrict__ Spart)
{
    __shared__ __align__(16) u16 Hh[128][72];
    __shared__ __align__(16) u16 Hl[128][72];

    const int t = threadIdx.x, lane = t & 63, w = t >> 6;   // w in {0..3}
    const int jb = blockIdx.x, b = jb & 15;
    const int l15 = lane & 15, quad = lane >> 4;
    const int i0 = w * 32;                       // wave's 32-i strip
    const int c4 = l15 * 4;

    // u row: loop-invariant per lane (one global float4, L1/L2-hot)
    const float4 uu = *(const float4*)(u + jb * 64 + c4);

    // H1 build: contiguous 8 KB stream per wave from v_t
    const float* vb = v_t + (b * 128 + i0) * 64;
    #pragma unroll
    for (int n = 0; n < 8; ++n) {
        const int idx = n * 64 + lane;
        const int il = idx >> 4;                  // c4 == (idx&15)*4 == l15*4
        const float4 vv = *(const float4*)(vb + idx * 4);
        const float a0 = lrelu(vv.x + uu.x), a1 = lrelu(vv.y + uu.y);
        const float a2 = lrelu(vv.z + uu.z), a3 = lrelu(vv.w + uu.w);
        u32 h01, l01, h23, l23;
        pack2x2(a0, a1, h01, l01);
        pack2x2(a2, a3, h23, l23);
        *(uint2*)&Hh[i0 + il][c4] = make_uint2(h01, h23);
        *(uint2*)&Hl[i0 + il][c4] = make_uint2(l01, l23);
    }

    const float* mbp[3] = {mb1, mb2, mb3};
    for (int layer = 0; layer < 3; ++layer) {
        floatx4 acc[4][2];                       // [mt=ch][nt=i]
        #pragma unroll
        for (int i = 0; i < 4; ++i)
            #pragma unroll
            for (int j = 0; j < 2; ++j) acc[i][j] = (floatx4)0.0f;

        #pragma unroll
        for (int kc = 0; kc < 2; ++kc) {
            short8 ah[4], al[4];
            #pragma unroll
            for (int mt = 0; mt < 4; ++mt) {
                const int aoff = (((layer * 4 + mt) * 2 + kc) * 64 + lane) * 8;
                ah[mt] = load_frag(w3fh + aoff);
                al[mt] = load_frag(w3fl + aoff);
            }
            const int k0 = kc * 32 + quad * 8;
            #pragma unroll
            for (int nt = 0; nt < 2; ++nt) {
                const short8 bh = load_frag(&Hh[i0 + nt * 16 + l15][k0]);
                const short8 bl = load_frag(&Hl[i0 + nt * 16 + l15][k0]);
                #pragma unroll
                for (int mt = 0; mt < 4; ++mt) {
                    acc[mt][nt] = mfma16(ah[mt], bh, acc[mt][nt]);
                    acc[mt][nt] = mfma16(ah[mt], bl, acc[mt][nt]);
                    acc[mt][nt] = mfma16(al[mt], bh, acc[mt][nt]);
                }
            }
        }

        if (layer < 2) {
            #pragma unroll
            for (int mt = 0; mt < 4; ++mt) {
                float bias[4];
                #pragma unroll
                for (int r = 0; r < 4; ++r) bias[r] = mbp[layer][mt * 16 + quad * 4 + r];
                #pragma unroll
                for (int nt = 0; nt < 2; ++nt) {
                    const int i = i0 + nt * 16 + l15;
                    const float v0 = lrelu(acc[mt][nt][0] + bias[0]);
                    const float v1 = lrelu(acc[mt][nt][1] + bias[1]);
                    const float v2 = lrelu(acc[mt][nt][2] + bias[2]);
                    const float v3 = lrelu(acc[mt][nt][3] + bias[3]);
                    u32 h01, l01, h23, l23;
                    pack2x2(v0, v1, h01, l01);
                    pack2x2(v2, v3, h23, l23);
                    *(uint2*)&Hh[i][mt * 16 + quad * 4] = make_uint2(h01, h23);
                    *(uint2*)&Hl[i][mt * 16 + quad * 4] = make_uint2(l01, l23);
                }
            }
        } else {
            // final layer: lrelu + reduce over this wave's 32 i
            #pragma unroll
            for (int mt = 0; mt < 4; ++mt) {
                float bias[4];
                #pragma unroll
                for (int r = 0; r < 4; ++r) bias[r] = mbp[2][mt * 16 + quad * 4 + r];
                float4 sv;
                #pragma unroll
                for (int r = 0; r < 4; ++r) {
                    float val = lrelu(acc[mt][0][r] + bias[r])
                              + lrelu(acc[mt][1][r] + bias[r]);
                    val += __shfl_xor(val, 1, 16);
                    val += __shfl_xor(val, 2, 16);
                    val += __shfl_xor(val, 4, 16);
                    val += __shfl_xor(val, 8, 16);
                    (&sv.x)[r] = val;
                }
                if (l15 == 0)
                    *(float4*)(Spart + jb * 256 + w * 64 + mt * 16 + quad * 4) = sv;
            }
        }
    }
}

// ---------------------------------------------------------------------------
// K4: head over 8 jb per block (weights amortized).
// S = 4 Spart quarters summed; T1 = lrelu(S@lw0t+lb0); out = lrelu(T1@lw1t+lb1).
// grid: 256 blocks, 256 thr.
// ---------------------------------------------------------------------------
__global__ __launch_bounds__(256) void k4_head(
    const float* __restrict__ Spart,
    const float* __restrict__ lw0t, const float* __restrict__ lb0,
    const float* __restrict__ lw1t, const float* __restrict__ lb1,
    float* __restrict__ out)
{
    __shared__ float Ss[8][64];
    __shared__ float T1[8][64];

    const int t = threadIdx.x;
    const int jb0 = blockIdx.x * 8;

    #pragma unroll
    for (int p = 0; p < 2; ++p) {
        const int idx = t + 256 * p;
        const int jbb = idx >> 6, ch = idx & 63;
        const float* sp = Spart + (jb0 + jbb) * 256 + ch;
        Ss[jbb][ch] = sp[0] + sp[64] + sp[128] + sp[192];
    }
    __syncthreads();

    #pragma unroll
    for (int p = 0; p < 2; ++p) {
        const int idx = t + 256 * p;
        const int jbb = idx >> 6, c = idx & 63;
        float a = lb0[c];
        #pragma unroll 8
        for (int k = 0; k < 64; ++k) a += Ss[jbb][k] * lw0t[k * 64 + c];
        T1[jbb][c] = lrelu(a);
    }
    __syncthreads();

    const int c = t;
    float acc[8];
    const float base = lb1[c];
    #pragma unroll
    for (int jbb = 0; jbb < 8; ++jbb) acc[jbb] = base;
    #pragma unroll 4
    for (int k = 0; k < 64; ++k) {
        const float wv = lw1t[k * 256 + c];
        #pragma unroll
        for (int jbb = 0; jbb < 8; ++jbb) acc[jbb] += T1[jbb][k] * wv;
    }
    #pragma unroll
    for (int jbb = 0; jbb < 8; ++jbb)
        out[(jb0 + jbb) * 256 + c] = lrelu(acc[jbb]);
}

// ---------------------------------------------------------------------------
extern "C" void kernel_launch(void* const* d_in, const int* in_sizes, int n_in,
                              void* d_out, int out_size, void* d_ws, size_t ws_size,
                              hipStream_t stream)
{
    const float* x   = (const float*)d_in[0];
    const float* cw0 = (const float*)d_in[1];
    const float* cb0 = (const float*)d_in[2];
    const float* cw1 = (const float*)d_in[3];
    const float* cb1 = (const float*)d_in[4];
    const float* cw2 = (const float*)d_in[5];
    const float* cb2 = (const float*)d_in[6];
    const float* cw3 = (const float*)d_in[7];
    const float* cb3 = (const float*)d_in[8];
    const float* mw0 = (const float*)d_in[9];
    const float* mb0 = (const float*)d_in[10];
    const float* mw1 = (const float*)d_in[11];
    const float* mb1 = (const float*)d_in[12];
    const float* mw2 = (const float*)d_in[13];
    const float* mb2 = (const float*)d_in[14];
    const float* mw3 = (const float*)d_in[15];
    const float* mb3 = (const float*)d_in[16];
    const float* lw0 = (const float*)d_in[17];
    const float* lb0 = (const float*)d_in[18];
    const float* lw1 = (const float*)d_in[19];
    const float* lb1 = (const float*)d_in[20];
    float* out = (float*)d_out;

    char* base = (char*)d_ws;
    u16* xfh   = (u16*)(base + 0);
    u16* xfl   = (u16*)(base + 2097152);
    u16* wcfh  = (u16*)(base + 4194304);
    u16* wcfl  = (u16*)(base + 5242880);
    u16* b2fh  = (u16*)(base + 6291456);
    u16* b2fl  = (u16*)(base + 6356992);
    u16* w3fh  = (u16*)(base + 6422528);
    u16* w3fl  = (u16*)(base + 6447104);
    float* lw0t  = (float*)(base + 6471680);
    float* lw1t  = (float*)(base + 6488064);
    u16* Ffh   = (u16*)(base + 6553600);
    u16* Ffl   = (u16*)(base + 7602176);
    float* u   = (float*)(base + 8650752);
    float* v_t = (float*)(base + 9175040);
    float* Spart = (float*)(base + 9699328);   // 2048*256*4 = 2 MB
    // total 11796480 bytes (~11.3 MB)

    hipLaunchKernelGGL(p0_prep, dim3(1600), dim3(256), 0, stream,
                       x, cw0, cw1, cw2, cw3, mw0, mw1, mw2, mw3, lw0, lw1,
                       xfh, xfl, wcfh, wcfl, b2fh, b2fl, w3fh, w3fl, lw0t, lw1t);
    hipLaunchKernelGGL(k1f_conv, dim3(64, 4), dim3(512), 0, stream,
                       xfh, xfl, wcfh, wcfl, cb0, cb1, cb2, cb3, Ffh, Ffl);
    hipLaunchKernelGGL(k2_uv, dim3(128, 2), dim3(256), 0, stream,
                       Ffh, Ffl, b2fh, b2fl, mb0, u, v_t);
    hipLaunchKernelGGL(k3_pair, dim3(2048), dim3(256), 0, stream,
                       u, v_t, w3fh, w3fl, mb1, mb2, mb3, Spart);
    hipLaunchKernelGGL(k4_head, dim3(256), dim3(256), 0, stream,
                       Spart, lw0t, lb0, lw1t, lb1, out);
}

// Round 12
// 153.683 us; speedup vs baseline: 1.0652x; 1.0204x over previous
//
#include <hip/hip_runtime.h>
#include <hip/hip_bf16.h>

#define SLOPE 0.1f
typedef unsigned short u16;
typedef unsigned int u32;
typedef __attribute__((ext_vector_type(8))) short short8;
typedef __attribute__((ext_vector_type(4))) float floatx4;

__device__ __forceinline__ float lrelu(float x) { return x > 0.0f ? x : SLOPE * x; }

// round-nearest split: x ~= hi + lo (bf16 each), rel err ~2^-17
__device__ __forceinline__ void split_rn(float x, u16* h, u16* l) {
    union { __hip_bfloat16 b; u16 u; } c1, c2;
    c1.b = __float2bfloat16(x);
    float hf = __bfloat162float(c1.b);
    c2.b = __float2bfloat16(x - hf);
    *h = c1.u; *l = c2.u;
}

// truncation split of a PAIR of fp32 -> packed hi-u32 and lo-u32 (v_perm pack)
__device__ __forceinline__ void pack2x2(float v0, float v1, u32& h, u32& l) {
    u32 a0 = __float_as_uint(v0), a1 = __float_as_uint(v1);
    h = __builtin_amdgcn_perm(a1, a0, 0x07060302u);   // [a0.hi16 | a1.hi16]
    float r0 = v0 - __uint_as_float(a0 & 0xFFFF0000u);
    float r1 = v1 - __uint_as_float(a1 & 0xFFFF0000u);
    l = __builtin_amdgcn_perm(__float_as_uint(r1), __float_as_uint(r0), 0x07060302u);
}

__device__ __forceinline__ short8 load_frag(const u16* p) {
    union { uint4 q; short8 s; } cv;
    cv.q = *(const uint4*)p;
    return cv.s;
}

__device__ __forceinline__ floatx4 mfma16(short8 a, short8 b, floatx4 c) {
    return __builtin_amdgcn_mfma_f32_16x16x32_bf16(a, b, c, 0, 0, 0);
}

// ---------------------------------------------------------------------------
// P0: one-shot preprocessing into FRAGMENT-LINEAR layouts, x4 vectorized.
// ---------------------------------------------------------------------------
__global__ __launch_bounds__(256) void p0_prep(
    const float* __restrict__ x,
    const float* __restrict__ cw0, const float* __restrict__ cw1,
    const float* __restrict__ cw2, const float* __restrict__ cw3,
    const float* __restrict__ mw0, const float* __restrict__ mw1,
    const float* __restrict__ mw2, const float* __restrict__ mw3,
    const float* __restrict__ lw0, const float* __restrict__ lw1,
    u16* __restrict__ xfh, u16* __restrict__ xfl,
    u16* __restrict__ wcfh, u16* __restrict__ wcfl,
    u16* __restrict__ b2fh, u16* __restrict__ b2fl,
    u16* __restrict__ w3fh, u16* __restrict__ w3fl,
    float* __restrict__ lw0t, float* __restrict__ lw1t)
{
    int idx = (blockIdx.x * 256 + threadIdx.x) * 4;
    if (idx < 1048576) {
        const int j = idx & 7, lane = (idx >> 3) & 63;
        const int kc = (idx >> 9) & 15, rt = idx >> 13;
        const int l15 = lane & 15, quad = lane >> 4;
        const float4 s = *(const float4*)(x + (rt * 16 + l15) * 512 + kc * 32 + quad * 8 + j);
        u16 h[4], l[4];
        split_rn(s.x, &h[0], &l[0]); split_rn(s.y, &h[1], &l[1]);
        split_rn(s.z, &h[2], &l[2]); split_rn(s.w, &h[3], &l[3]);
        *(ushort4*)(xfh + idx) = make_ushort4(h[0], h[1], h[2], h[3]);
        *(ushort4*)(xfl + idx) = make_ushort4(l[0], l[1], l[2], l[3]);
        return;
    }
    idx -= 1048576;
    if (idx < 524288) {
        const int j = idx & 7, lane = (idx >> 3) & 63;
        const int kc = (idx >> 9) & 15, nt = (idx >> 13) & 3, slot = idx >> 15;
        int branch, base;
        if (slot == 0)      { branch = 0; base = 0; }
        else if (slot < 4)  { branch = 1; base = 1; }
        else if (slot < 9)  { branch = 2; base = 4; }
        else                { branch = 3; base = 9; }
        const int dk = slot - base, ksz = 2 * branch + 1;
        const float* cw = branch == 0 ? cw0 : branch == 1 ? cw1 : branch == 2 ? cw2 : cw3;
        const int c = nt * 16 + (lane & 15);
        const int e = kc * 32 + (lane >> 4) * 8 + j;
        const float4 s = *(const float4*)(cw + (c * ksz + dk) * 512 + e);
        u16 h[4], l[4];
        split_rn(s.x, &h[0], &l[0]); split_rn(s.y, &h[1], &l[1]);
        split_rn(s.z, &h[2], &l[2]); split_rn(s.w, &h[3], &l[3]);
        *(ushort4*)(wcfh + idx) = make_ushort4(h[0], h[1], h[2], h[3]);
        *(ushort4*)(wcfl + idx) = make_ushort4(l[0], l[1], l[2], l[3]);
        return;
    }
    idx -= 524288;
    if (idx < 32768) {
        const int j = idx & 7, lane = (idx >> 3) & 63;
        const int kc = (idx >> 9) & 7, nt = (idx >> 12) & 3, nh = idx >> 14;
        const int n = nh * 64 + nt * 16 + (lane & 15);
        const int k = kc * 32 + (lane >> 4) * 8 + j;
        const float4 s = *(const float4*)(mw0 + (n & 63) * 512 + (n >> 6) * 256 + k);
        u16 h[4], l[4];
        split_rn(s.x, &h[0], &l[0]); split_rn(s.y, &h[1], &l[1]);
        split_rn(s.z, &h[2], &l[2]); split_rn(s.w, &h[3], &l[3]);
        *(ushort4*)(b2fh + idx) = make_ushort4(h[0], h[1], h[2], h[3]);
        *(ushort4*)(b2fl + idx) = make_ushort4(l[0], l[1], l[2], l[3]);
        return;
    }
    idx -= 32768;
    if (idx < 12288) {
        const int j = idx & 7, lane = (idx >> 3) & 63;
        const int kc = (idx >> 9) & 1, mt = (idx >> 10) & 3, layer = idx >> 12;
        const float* mw = layer == 0 ? mw1 : layer == 1 ? mw2 : mw3;
        const int ch = mt * 16 + (lane & 15);
        const int k = kc * 32 + (lane >> 4) * 8 + j;
        const float4 s = *(const float4*)(mw + ch * 64 + k);
        u16 h[4], l[4];
        split_rn(s.x, &h[0], &l[0]); split_rn(s.y, &h[1], &l[1]);
        split_rn(s.z, &h[2], &l[2]); split_rn(s.w, &h[3], &l[3]);
        *(ushort4*)(w3fh + idx) = make_ushort4(h[0], h[1], h[2], h[3]);
        *(ushort4*)(w3fl + idx) = make_ushort4(l[0], l[1], l[2], l[3]);
        return;
    }
    idx -= 12288;
    if (idx < 4096) {
        const int k = idx >> 6, n = idx & 63;
        float4 o;
        o.x = lw0[(n + 0) * 64 + k]; o.y = lw0[(n + 1) * 64 + k];
        o.z = lw0[(n + 2) * 64 + k]; o.w = lw0[(n + 3) * 64 + k];
        *(float4*)(lw0t + idx) = o;
        return;
    }
    idx -= 4096;
    if (idx < 16384) {
        const int k = idx >> 8, n = idx & 255;
        float4 o;
        o.x = lw1[(n + 0) * 64 + k]; o.y = lw1[(n + 1) * 64 + k];
        o.z = lw1[(n + 2) * 64 + k]; o.w = lw1[(n + 3) * 64 + k];
        *(float4*)(lw1t + idx) = o;
        return;
    }
}

// ---------------------------------------------------------------------------
// K1f: fused conv GEMM, 2-rt tiling (PROVEN R8/R11): block = (rt-pair,
// branch), 512 thr = 8 waves, K-split 8-way over (dk,kc) units.  B (weight)
// frags loaded once per unit and reused for both rt -> weight L2 traffic
// halved.  grid: (64, 4).
// ---------------------------------------------------------------------------
__global__ __launch_bounds__(512) void k1f_conv(
    const u16* __restrict__ xfh, const u16* __restrict__ xfl,
    const u16* __restrict__ wcfh, const u16* __restrict__ wcfl,
    const float* __restrict__ cb0, const float* __restrict__ cb1,
    const float* __restrict__ cb2, const float* __restrict__ cb3,
    u16* __restrict__ Ffh, u16* __restrict__ Ffl)
{
    __shared__ float P[8][16][72];   // 36.9 KB

    const int t = threadIdx.x, lane = t & 63, w = t >> 6;   // 8 waves
    const int rtp = blockIdx.x;                // 0..63 -> rt, rt+64
    const int br = blockIdx.y;                 // 0..3
    const int base = br * br;                  // 0,1,4,9
    const int ksz = 2 * br + 1;
    const int l15 = lane & 15, quad = lane >> 4;

    floatx4 acc[2][4];
    #pragma unroll
    for (int r = 0; r < 2; ++r)
        #pragma unroll
        for (int j = 0; j < 4; ++j) acc[r][j] = (floatx4)0.0f;

    const int nunits = ksz * 16;
    for (int unit = w; unit < nunits; unit += 8) {
        const int dk = unit >> 4, kc = unit & 15;
        const int slot = base + dk;
        short8 bh[4], bl[4];
        #pragma unroll
        for (int nt = 0; nt < 4; ++nt) {
            const int boff = (((slot * 4 + nt) * 16 + kc) * 64 + lane) * 8;
            bh[nt] = load_frag(wcfh + boff);
            bl[nt] = load_frag(wcfl + boff);
        }
        #pragma unroll
        for (int r = 0; r < 2; ++r) {
            const int rts = rtp + r * 64 + dk - br;
            if (rts < 0 || rts >= 128) continue;
            const int aoff = ((rts * 16 + kc) * 64 + lane) * 8;
            const short8 ah = load_frag(xfh + aoff);
            const short8 al = load_frag(xfl + aoff);
            #pragma unroll
            for (int nt = 0; nt < 4; ++nt) {
                acc[r][nt] = mfma16(ah, bh[nt], acc[r][nt]);
                acc[r][nt] = mfma16(ah, bl[nt], acc[r][nt]);
                acc[r][nt] = mfma16(al, bh[nt], acc[r][nt]);
            }
        }
    }

    const float* cb = br == 0 ? cb0 : br == 1 ? cb1 : br == 2 ? cb2 : cb3;
    #pragma unroll
    for (int r = 0; r < 2; ++r) {
        #pragma unroll
        for (int nt = 0; nt < 4; ++nt)
            #pragma unroll
            for (int rr = 0; rr < 4; ++rr)
                P[w][quad * 4 + rr][nt * 16 + l15] = acc[r][nt][rr];
        __syncthreads();
        if (t < 256) {
            const int row = t >> 4, c4 = (t & 15) * 4;
            u16 h4[4], l4[4];
            #pragma unroll
            for (int i = 0; i < 4; ++i) {
                float val = cb[c4 + i];
                #pragma unroll
                for (int ww = 0; ww < 8; ++ww) val += P[ww][row][c4 + i];
                split_rn(lrelu(val), &h4[i], &l4[i]);
            }
            const int rt = rtp + r * 64;
            const int m4 = br * 64 + c4;
            const int dst = ((rt * 8 + (m4 >> 5)) * 64 + ((m4 >> 3) & 3) * 16 + row) * 8 + (m4 & 7);
            *(ushort4*)(Ffh + dst) = make_ushort4(h4[0], h4[1], h4[2], h4[3]);
            *(ushort4*)(Ffl + dst) = make_ushort4(l4[0], l4[1], l4[2], l4[3]);
        }
        __syncthreads();
    }
}

// ---------------------------------------------------------------------------
// K2: [u|v] = F @ B2^T.  grid (128 rt, 2 nh); 4 waves, each 2 kc; LDS reduce.
// u gets +mb0; v written transposed (b-major) as v_t.
// ---------------------------------------------------------------------------
__global__ __launch_bounds__(256) void k2_uv(
    const u16* __restrict__ Ffh, const u16* __restrict__ Ffl,
    const u16* __restrict__ b2fh, const u16* __restrict__ b2fl,
    const float* __restrict__ mb0,
    float* __restrict__ u, float* __restrict__ v_t)
{
    __shared__ float P[4][16][72];

    const int t = threadIdx.x, lane = t & 63, w = t >> 6;
    const int rt = blockIdx.x;
    const int nh = blockIdx.y;
    const int l15 = lane & 15, quad = lane >> 4;

    floatx4 acc[4];
    #pragma unroll
    for (int j = 0; j < 4; ++j) acc[j] = (floatx4)0.0f;

    #pragma unroll
    for (int kk = 0; kk < 2; ++kk) {
        const int kc = w * 2 + kk;
        const int aoff = ((rt * 8 + kc) * 64 + lane) * 8;
        const short8 ah = load_frag(Ffh + aoff);
        const short8 al = load_frag(Ffl + aoff);
        #pragma unroll
        for (int nt = 0; nt < 4; ++nt) {
            const int boff = (((nh * 4 + nt) * 8 + kc) * 64 + lane) * 8;
            const short8 bh = load_frag(b2fh + boff);
            const short8 bl = load_frag(b2fl + boff);
            acc[nt] = mfma16(ah, bh, acc[nt]);
            acc[nt] = mfma16(ah, bl, acc[nt]);
            acc[nt] = mfma16(al, bh, acc[nt]);
        }
    }

    #pragma unroll
    for (int nt = 0; nt < 4; ++nt)
        #pragma unroll
        for (int r = 0; r < 4; ++r)
            P[w][quad * 4 + r][nt * 16 + l15] = acc[nt][r];
    __syncthreads();

    const int row = t >> 4, c4 = (t & 15) * 4;
    const int rglob = rt * 16 + row;
    float4 oo;
    #pragma unroll
    for (int i = 0; i < 4; ++i)
        (&oo.x)[i] = P[0][row][c4 + i] + P[1][row][c4 + i]
                   + P[2][row][c4 + i] + P[3][row][c4 + i];
    if (nh == 0) {
        oo.x += mb0[c4 + 0]; oo.y += mb0[c4 + 1];
        oo.z += mb0[c4 + 2]; oo.w += mb0[c4 + 3];
        *(float4*)(u + rglob * 64 + c4) = oo;
    } else {
        const int i = rglob >> 4, b = rglob & 15;
        *(float4*)(v_t + (b * 128 + i) * 64 + c4) = oo;
    }
}

// ---------------------------------------------------------------------------
// K3 (R9 fused-head variant — measured 1.8 us faster than split k3+k4 in the
// R9-vs-R10 A/B): per jb, 4 waves x 32 i's; H bf16 hi/lo in LDS, rows
// wave-private; barrier-free through the 3 MFMA layers.  Layer-3 reduced over
// own 32 i in regs (shfl) -> Sp quarters in LDS, then head fused in-block:
// S = sum quarters; T1 = lrelu(S@lw0t+lb0); out = lrelu(T1@lw1t+lb1).
// grid: 2048 blocks, 256 thr; LDS 38.4 KB -> 4 blocks/CU -> 16 waves/CU.
// ---------------------------------------------------------------------------
__global__ __launch_bounds__(256, 4) void k3_pair(
    const float* __restrict__ u, const float* __restrict__ v_t,
    const u16* __restrict__ w3fh, const u16* __restrict__ w3fl,
    const float* __restrict__ mb1, const float* __restrict__ mb2,
    const float* __restrict__ mb3,
    const float* __restrict__ lw0t, const float* __restrict__ lb0,
    const float* __restrict__ lw1t, const float* __restrict__ lb1,
    float* __restrict__ out)
{
    __shared__ __align__(16) u16 Hh[128][72];
    __shared__ __align__(16) u16 Hl[128][72];
    __shared__ float Sp[4][64];
    __shared__ float Ss[64];
    __shared__ float T1[64];

    const int t = threadIdx.x, lane = t & 63, w = t >> 6;   // w in {0..3}
    const int jb = blockIdx.x, b = jb & 15;
    const int l15 = lane & 15, quad = lane >> 4;
    const int i0 = w * 32;                       // wave's 32-i strip
    const int c4 = l15 * 4;

    // u row: loop-invariant per lane (one global float4, L1/L2-hot)
    const float4 uu = *(const float4*)(u + jb * 64 + c4);

    // H1 build: contiguous 8 KB stream per wave from v_t
    const float* vb = v_t + (b * 128 + i0) * 64;
    #pragma unroll
    for (int n = 0; n < 8; ++n) {
        const int idx = n * 64 + lane;
        const int il = idx >> 4;                  // c4 == (idx&15)*4 == l15*4
        const float4 vv = *(const float4*)(vb + idx * 4);
        const float a0 = lrelu(vv.x + uu.x), a1 = lrelu(vv.y + uu.y);
        const float a2 = lrelu(vv.z + uu.z), a3 = lrelu(vv.w + uu.w);
        u32 h01, l01, h23, l23;
        pack2x2(a0, a1, h01, l01);
        pack2x2(a2, a3, h23, l23);
        *(uint2*)&Hh[i0 + il][c4] = make_uint2(h01, h23);
        *(uint2*)&Hl[i0 + il][c4] = make_uint2(l01, l23);
    }

    const float* mbp[3] = {mb1, mb2, mb3};
    for (int layer = 0; layer < 3; ++layer) {
        floatx4 acc[4][2];                       // [mt=ch][nt=i]
        #pragma unroll
        for (int i = 0; i < 4; ++i)
            #pragma unroll
            for (int j = 0; j < 2; ++j) acc[i][j] = (floatx4)0.0f;

        #pragma unroll
        for (int kc = 0; kc < 2; ++kc) {
            short8 ah[4], al[4];
            #pragma unroll
            for (int mt = 0; mt < 4; ++mt) {
                const int aoff = (((layer * 4 + mt) * 2 + kc) * 64 + lane) * 8;
                ah[mt] = load_frag(w3fh + aoff);
                al[mt] = load_frag(w3fl + aoff);
            }
            const int k0 = kc * 32 + quad * 8;
            #pragma unroll
            for (int nt = 0; nt < 2; ++nt) {
                const short8 bh = load_frag(&Hh[i0 + nt * 16 + l15][k0]);
                const short8 bl = load_frag(&Hl[i0 + nt * 16 + l15][k0]);
                #pragma unroll
                for (int mt = 0; mt < 4; ++mt) {
                    acc[mt][nt] = mfma16(ah[mt], bh, acc[mt][nt]);
                    acc[mt][nt] = mfma16(ah[mt], bl, acc[mt][nt]);
                    acc[mt][nt] = mfma16(al[mt], bh, acc[mt][nt]);
                }
            }
        }

        if (layer < 2) {
            #pragma unroll
            for (int mt = 0; mt < 4; ++mt) {
                float bias[4];
                #pragma unroll
                for (int r = 0; r < 4; ++r) bias[r] = mbp[layer][mt * 16 + quad * 4 + r];
                #pragma unroll
                for (int nt = 0; nt < 2; ++nt) {
                    const int i = i0 + nt * 16 + l15;
                    const float v0 = lrelu(acc[mt][nt][0] + bias[0]);
                    const float v1 = lrelu(acc[mt][nt][1] + bias[1]);
                    const float v2 = lrelu(acc[mt][nt][2] + bias[2]);
                    const float v3 = lrelu(acc[mt][nt][3] + bias[3]);
                    u32 h01, l01, h23, l23;
                    pack2x2(v0, v1, h01, l01);
                    pack2x2(v2, v3, h23, l23);
                    *(uint2*)&Hh[i][mt * 16 + quad * 4] = make_uint2(h01, h23);
                    *(uint2*)&Hl[i][mt * 16 + quad * 4] = make_uint2(l01, l23);
                }
            }
        } else {
            // final layer: lrelu + reduce over this wave's 32 i -> Sp[w]
            #pragma unroll
            for (int mt = 0; mt < 4; ++mt) {
                float bias[4];
                #pragma unroll
                for (int r = 0; r < 4; ++r) bias[r] = mbp[2][mt * 16 + quad * 4 + r];
                float4 sv;
                #pragma unroll
                for (int r = 0; r < 4; ++r) {
                    float val = lrelu(acc[mt][0][r] + bias[r])
                              + lrelu(acc[mt][1][r] + bias[r]);
                    val += __shfl_xor(val, 1, 16);
                    val += __shfl_xor(val, 2, 16);
                    val += __shfl_xor(val, 4, 16);
                    val += __shfl_xor(val, 8, 16);
                    (&sv.x)[r] = val;
                }
                if (l15 == 0)
                    *(float4*)(&Sp[w][mt * 16 + quad * 4]) = sv;
            }
        }
    }

    // fused head
    __syncthreads();
    if (t < 64) Ss[t] = Sp[0][t] + Sp[1][t] + Sp[2][t] + Sp[3][t];
    __syncthreads();
    if (t < 64) {
        float a = lb0[t];
        #pragma unroll 8
        for (int k = 0; k < 64; ++k) a += Ss[k] * lw0t[k * 64 + t];
        T1[t] = lrelu(a);
    }
    __syncthreads();
    {
        float a = lb1[t];
        #pragma unroll 8
        for (int k = 0; k < 64; ++k) a += T1[k] * lw1t[k * 256 + t];
        out[jb * 256 + t] = lrelu(a);
    }
}

// ---------------------------------------------------------------------------
extern "C" void kernel_launch(void* const* d_in, const int* in_sizes, int n_in,
                              void* d_out, int out_size, void* d_ws, size_t ws_size,
                              hipStream_t stream)
{
    const float* x   = (const float*)d_in[0];
    const float* cw0 = (const float*)d_in[1];
    const float* cb0 = (const float*)d_in[2];
    const float* cw1 = (const float*)d_in[3];
    const float* cb1 = (const float*)d_in[4];
    const float* cw2 = (const float*)d_in[5];
    const float* cb2 = (const float*)d_in[6];
    const float* cw3 = (const float*)d_in[7];
    const float* cb3 = (const float*)d_in[8];
    const float* mw0 = (const float*)d_in[9];
    const float* mb0 = (const float*)d_in[10];
    const float* mw1 = (const float*)d_in[11];
    const float* mb1 = (const float*)d_in[12];
    const float* mw2 = (const float*)d_in[13];
    const float* mb2 = (const float*)d_in[14];
    const float* mw3 = (const float*)d_in[15];
    const float* mb3 = (const float*)d_in[16];
    const float* lw0 = (const float*)d_in[17];
    const float* lb0 = (const float*)d_in[18];
    const float* lw1 = (const float*)d_in[19];
    const float* lb1 = (const float*)d_in[20];
    float* out = (float*)d_out;

    char* base = (char*)d_ws;
    u16* xfh   = (u16*)(base + 0);
    u16* xfl   = (u16*)(base + 2097152);
    u16* wcfh  = (u16*)(base + 4194304);
    u16* wcfl  = (u16*)(base + 5242880);
    u16* b2fh  = (u16*)(base + 6291456);
    u16* b2fl  = (u16*)(base + 6356992);
    u16* w3fh  = (u16*)(base + 6422528);
    u16* w3fl  = (u16*)(base + 6447104);
    float* lw0t  = (float*)(base + 6471680);
    float* lw1t  = (float*)(base + 6488064);
    u16* Ffh   = (u16*)(base + 6553600);
    u16* Ffl   = (u16*)(base + 7602176);
    float* u   = (float*)(base + 8650752);
    float* v_t = (float*)(base + 9175040);
    // total 9699328 bytes (~9.3 MB)

    hipLaunchKernelGGL(p0_prep, dim3(1600), dim3(256), 0, stream,
                       x, cw0, cw1, cw2, cw3, mw0, mw1, mw2, mw3, lw0, lw1,
                       xfh, xfl, wcfh, wcfl, b2fh, b2fl, w3fh, w3fl, lw0t, lw1t);
    hipLaunchKernelGGL(k1f_conv, dim3(64, 4), dim3(512), 0, stream,
                       xfh, xfl, wcfh, wcfl, cb0, cb1, cb2, cb3, Ffh, Ffl);
    hipLaunchKernelGGL(k2_uv, dim3(128, 2), dim3(256), 0, stream,
                       Ffh, Ffl, b2fh, b2fl, mb0, u, v_t);
    hipLaunchKernelGGL(k3_pair, dim3(2048), dim3(256), 0, stream,
                       u, v_t, w3fh, w3fl, mb1, mb2, mb3, lw0t, lb0, lw1t, lb1, out);
}